// Round 1
// baseline (70.076 us; speedup 1.0000x reference)
//
#include <hip/hip_runtime.h>
#include <hip/hip_bf16.h>

// CatEmbedder: B=4096, L=128, D=64, NG=NL=2, PROBE=1 -> 1/(L+1)=1/129, ALPHA=0.5
// Structure:
//   t[k]   = (emb_table[k] @ acc_w) / 129                       (128 x 64 table)
//   s[b]   = sum_l emb_table[idx[b,l]]
//   u[b]   = (s[b] @ acc_w)/129 + acc_b
//   g0     = relu(u[b] + t[idx[b,l]])
//   g2     = (relu(g0 @ gw0^T + gb0)) @ gw1^T + gb1
//   loc    = 0.5*(s^2 - sum emb^2) -> 2-layer MLP (lw, lb)
//   out    = 0.5*g2 + 0.5*loc2[b]

typedef __attribute__((ext_vector_type(8))) short bf16x8;
typedef __attribute__((ext_vector_type(4))) float f32x4;

#define RECIP129 (1.0f/129.0f)

static __device__ __forceinline__ unsigned short f2bf(float x){
  unsigned int u = __float_as_uint(x);
  u += 0x7fffu + ((u >> 16) & 1u);     // round-to-nearest-even
  return (unsigned short)(u >> 16);
}

// ---------------- prep: tsup table + lw transposes -------------------------
__global__ __launch_bounds__(64) void prep_kernel(const float* __restrict__ emb,
                                                  const float* __restrict__ acc_w,
                                                  const float* __restrict__ lw,
                                                  float* __restrict__ tsup,
                                                  float* __restrict__ lwT){
  int e = threadIdx.x;
  int blk = blockIdx.x;
  if (blk < 128){
    float acc = 0.f;
    #pragma unroll
    for (int d = 0; d < 64; ++d) acc += emb[blk*64 + d] * acc_w[d*64 + e];
    tsup[blk*64 + e] = acc * RECIP129;
  } else {
    int layer = blk - 128;               // 0 or 1
    const float* w = lw + layer*4096;
    float* wt = lwT + layer*4096;
    #pragma unroll
    for (int d = 0; d < 64; ++d) wt[d*64 + e] = w[e*64 + d];
  }
}

// ---------------- per-batch: s, u[b], loc2[b] -------------------------------
__global__ __launch_bounds__(256) void perb_kernel(const int* __restrict__ cat,
                                                   const float* __restrict__ emb,
                                                   const float* __restrict__ acc_w,
                                                   const float* __restrict__ acc_b,
                                                   const float* __restrict__ lwT,
                                                   const float* __restrict__ lb,
                                                   float* __restrict__ u_out,
                                                   float* __restrict__ loc2_out){
  const int lane = threadIdx.x & 63;
  const int b = blockIdx.x*4 + (threadIdx.x >> 6);

  int k0 = cat[b*128 + lane];
  int k1 = cat[b*128 + 64 + lane];

  float s = 0.f, sq = 0.f;
  #pragma unroll 8
  for (int l = 0; l < 64; ++l){
    int k = __shfl(k0, l);
    float e = emb[k*64 + lane];
    s += e; sq += e*e;
  }
  #pragma unroll 8
  for (int l = 0; l < 64; ++l){
    int k = __shfl(k1, l);
    float e = emb[k*64 + lane];
    s += e; sq += e*e;
  }

  // u[b,e] = (sum_d s[d]*acc_w[d,e]) / 129 + acc_b[e]
  float ua = 0.f;
  #pragma unroll 8
  for (int d = 0; d < 64; ++d) ua += __shfl(s, d) * acc_w[d*64 + lane];
  u_out[(size_t)b*64 + lane] = ua * RECIP129 + acc_b[lane];

  // local branch
  float loc0 = 0.5f*(s*s - sq);
  float a1 = 0.f;
  #pragma unroll 8
  for (int d = 0; d < 64; ++d) a1 += __shfl(loc0, d) * lwT[d*64 + lane];
  a1 = fmaxf(a1 + lb[lane], 0.f);
  float a2 = 0.f;
  #pragma unroll 8
  for (int d = 0; d < 64; ++d) a2 += __shfl(a1, d) * lwT[4096 + d*64 + lane];
  loc2_out[(size_t)b*64 + lane] = a2 + lb[64 + lane];
}

// ---------------- main: per-(b,l) 2-layer MLP via MFMA ----------------------
// wave = one b; 8 tiles of 16 rows; weights as B-fragments in registers.
__global__ __launch_bounds__(256) void fused_kernel(const int* __restrict__ cat,
                                                    const float* __restrict__ tsup,
                                                    const float* __restrict__ u_arr,
                                                    const float* __restrict__ loc2,
                                                    const float* __restrict__ gw,
                                                    const float* __restrict__ gb,
                                                    float* __restrict__ out){
  __shared__ __align__(16) float lds[4][64*20];   // per-wave g1 buffer, col-major stride 20
  const int tid  = threadIdx.x;
  const int wid  = tid >> 6, lane = tid & 63;
  const int b    = blockIdx.x*4 + wid;
  const int r    = lane & 15, h = lane >> 4;
  float* Lp = &lds[wid][0];

  // u[b] fragments (A-layout rows all share these; depends only on h)
  float uf[16];
  #pragma unroll
  for (int kc = 0; kc < 2; ++kc){
    const float4* up = reinterpret_cast<const float4*>(u_arr + (size_t)b*64 + kc*32 + h*8);
    float4 u0 = up[0], u1 = up[1];
    uf[kc*8+0]=u0.x; uf[kc*8+1]=u0.y; uf[kc*8+2]=u0.z; uf[kc*8+3]=u0.w;
    uf[kc*8+4]=u1.x; uf[kc*8+5]=u1.y; uf[kc*8+6]=u1.z; uf[kc*8+7]=u1.w;
  }

  // weight B-fragments: B[k][n] = gw[n][k]; lane holds col n = nt*16+r, k = kc*32+h*8+j
  bf16x8 w0[4][2], w1[4][2];
  #pragma unroll
  for (int nt = 0; nt < 4; ++nt){
    #pragma unroll
    for (int kc = 0; kc < 2; ++kc){
      const float* p0 = gw + (nt*16 + r)*64 + kc*32 + h*8;
      float4 a = *reinterpret_cast<const float4*>(p0);
      float4 c = *reinterpret_cast<const float4*>(p0 + 4);
      bf16x8 v;
      v[0]=(short)f2bf(a.x); v[1]=(short)f2bf(a.y); v[2]=(short)f2bf(a.z); v[3]=(short)f2bf(a.w);
      v[4]=(short)f2bf(c.x); v[5]=(short)f2bf(c.y); v[6]=(short)f2bf(c.z); v[7]=(short)f2bf(c.w);
      w0[nt][kc] = v;
      a = *reinterpret_cast<const float4*>(p0 + 4096);
      c = *reinterpret_cast<const float4*>(p0 + 4100);
      v[0]=(short)f2bf(a.x); v[1]=(short)f2bf(a.y); v[2]=(short)f2bf(a.z); v[3]=(short)f2bf(a.w);
      v[4]=(short)f2bf(c.x); v[5]=(short)f2bf(c.y); v[6]=(short)f2bf(c.z); v[7]=(short)f2bf(c.w);
      w1[nt][kc] = v;
    }
  }

  float gb0v[4], gb1v[4], lcv[4];
  #pragma unroll
  for (int nt = 0; nt < 4; ++nt){
    gb0v[nt] = gb[nt*16 + r];
    gb1v[nt] = gb[64 + nt*16 + r];
    lcv[nt]  = 0.5f * loc2[(size_t)b*64 + nt*16 + r];
  }

  for (int tl = 0; tl < 8; ++tl){
    const int rowbase = b*128 + tl*16;
    const int k = cat[rowbase + r];

    // A0 fragment: g0[row=r][k-dim] = relu(u + t[idx])
    bf16x8 a0[2];
    #pragma unroll
    for (int kc = 0; kc < 2; ++kc){
      const float* tp = tsup + k*64 + kc*32 + h*8;
      float4 t0 = *reinterpret_cast<const float4*>(tp);
      float4 t1 = *reinterpret_cast<const float4*>(tp + 4);
      float g[8] = {t0.x,t0.y,t0.z,t0.w,t1.x,t1.y,t1.z,t1.w};
      bf16x8 v;
      #pragma unroll
      for (int j = 0; j < 8; ++j){
        float x = fmaxf(g[j] + uf[kc*8+j], 0.f);
        v[j] = (short)f2bf(x);
      }
      a0[kc] = v;
    }

    // layer 1
    f32x4 acc[4];
    #pragma unroll
    for (int nt = 0; nt < 4; ++nt){ acc[nt][0]=gb0v[nt]; acc[nt][1]=gb0v[nt]; acc[nt][2]=gb0v[nt]; acc[nt][3]=gb0v[nt]; }
    #pragma unroll
    for (int kc = 0; kc < 2; ++kc)
      #pragma unroll
      for (int nt = 0; nt < 4; ++nt)
        acc[nt] = __builtin_amdgcn_mfma_f32_16x16x32_bf16(a0[kc], w0[nt][kc], acc[nt], 0, 0, 0);

    // relu -> LDS (col-major [col][row], stride 20 words: 16B-aligned b128, ~2-way banks)
    #pragma unroll
    for (int nt = 0; nt < 4; ++nt){
      f32x4 v = acc[nt];
      v[0]=fmaxf(v[0],0.f); v[1]=fmaxf(v[1],0.f); v[2]=fmaxf(v[2],0.f); v[3]=fmaxf(v[3],0.f);
      *reinterpret_cast<f32x4*>(Lp + (nt*16 + r)*20 + h*4) = v;   // col = nt*16+r, rows h*4..h*4+3
    }

    // A1 fragment: lane needs g1[row=r][k = kc*32+h*8+j]  (same-wave LDS, no barrier)
    bf16x8 a1[2];
    #pragma unroll
    for (int kc = 0; kc < 2; ++kc){
      bf16x8 v;
      #pragma unroll
      for (int j = 0; j < 8; ++j)
        v[j] = (short)f2bf(Lp[(kc*32 + h*8 + j)*20 + r]);
      a1[kc] = v;
    }

    // layer 2
    f32x4 acc2[4];
    #pragma unroll
    for (int nt = 0; nt < 4; ++nt){ acc2[nt][0]=gb1v[nt]; acc2[nt][1]=gb1v[nt]; acc2[nt][2]=gb1v[nt]; acc2[nt][3]=gb1v[nt]; }
    #pragma unroll
    for (int kc = 0; kc < 2; ++kc)
      #pragma unroll
      for (int nt = 0; nt < 4; ++nt)
        acc2[nt] = __builtin_amdgcn_mfma_f32_16x16x32_bf16(a1[kc], w1[nt][kc], acc2[nt], 0, 0, 0);

    // epilogue: out = 0.5*g2 + 0.5*loc2  (D layout: col = nt*16+r, row = h*4+reg)
    #pragma unroll
    for (int nt = 0; nt < 4; ++nt){
      #pragma unroll
      for (int reg = 0; reg < 4; ++reg){
        out[(size_t)(rowbase + h*4 + reg)*64 + nt*16 + r] = 0.5f*acc2[nt][reg] + lcv[nt];
      }
    }
  }
}

extern "C" void kernel_launch(void* const* d_in, const int* in_sizes, int n_in,
                              void* d_out, int out_size, void* d_ws, size_t ws_size,
                              hipStream_t stream) {
  const int*   cat   = (const int*)  d_in[0];
  const float* emb   = (const float*)d_in[1];
  const float* acc_w = (const float*)d_in[2];
  const float* acc_b = (const float*)d_in[3];
  const float* gw    = (const float*)d_in[4];
  const float* gb    = (const float*)d_in[5];
  const float* lw    = (const float*)d_in[6];
  const float* lb    = (const float*)d_in[7];
  float* out = (float*)d_out;

  const int B = in_sizes[0] / 128;   // 4096

  float* ws   = (float*)d_ws;
  float* tsup = ws;                      // 128*64
  float* lwT  = ws + 8192;               // 2*64*64
  float* u    = ws + 16384;              // B*64
  float* loc2 = u + (size_t)B*64;        // B*64

  hipLaunchKernelGGL(prep_kernel, dim3(130), dim3(64), 0, stream,
                     emb, acc_w, lw, tsup, lwT);
  hipLaunchKernelGGL(perb_kernel, dim3(B/4), dim3(256), 0, stream,
                     cat, emb, acc_w, acc_b, lwT, lb, u, loc2);
  hipLaunchKernelGGL(fused_kernel, dim3(B/4), dim3(256), 0, stream,
                     cat, tsup, u, loc2, gw, gb, out);
}

// Round 2
// 66.202 us; speedup vs baseline: 1.0585x; 1.0585x over previous
//
#include <hip/hip_runtime.h>
#include <hip/hip_bf16.h>

// CatEmbedder: B=4096, L=128, D=64, PROBE=1 -> 1/129, ALPHA=0.5
//   tsup[k] = (emb_table[k] @ acc_w) / 129              (128 x 64)
//   u[b]    = sum_l tsup[idx[b,l]] + acc_b              (linearity of adj)
//   g0      = relu(u[b] + tsup[idx[b,l]])
//   g2      = relu(g0 @ gw0^T + gb0) @ gw1^T + gb1
//   loc     = 0.5*(s^2 - sum e^2) -> 2-layer MLP (lwT, lb)
//   out     = 0.5*g2 + 0.5*loc2[b]

typedef __attribute__((ext_vector_type(8))) short bf16x8;
typedef __attribute__((ext_vector_type(4))) float f32x4;
typedef __attribute__((ext_vector_type(2))) unsigned int u32x2;

#define RECIP129 (1.0f/129.0f)

static __device__ __forceinline__ unsigned short f2bf(float x){
  unsigned int u = __float_as_uint(x);
  u += 0x7fffu + ((u >> 16) & 1u);     // RNE
  return (unsigned short)(u >> 16);
}

// ---------------- prep: tsup (f32) + lw transposes --------------------------
__global__ __launch_bounds__(64) void prep_kernel(const float* __restrict__ emb,
                                                  const float* __restrict__ acc_w,
                                                  const float* __restrict__ lw,
                                                  float* __restrict__ tsup,
                                                  float* __restrict__ lwT){
  int e = threadIdx.x;
  int blk = blockIdx.x;
  if (blk < 128){
    float acc = 0.f;
    #pragma unroll
    for (int d = 0; d < 64; ++d) acc += emb[blk*64 + d] * acc_w[d*64 + e];
    tsup[blk*64 + e] = acc * RECIP129;
  } else {
    int layer = blk - 128;
    const float* w = lw + layer*4096;
    float* wt = lwT + layer*4096;
    #pragma unroll
    for (int d = 0; d < 64; ++d) wt[d*64 + e] = w[e*64 + d];
  }
}

// ---------------- fused: everything per-b ----------------------------------
__global__ __launch_bounds__(256) void fused_kernel(
    const int*   __restrict__ cat,
    const float* __restrict__ emb,
    const float* __restrict__ tsupg,
    const float* __restrict__ acc_b,
    const float* __restrict__ lwT,
    const float* __restrict__ lb,
    const float* __restrict__ gwp,
    const float* __restrict__ gbias,
    float*       __restrict__ out)
{
  // tsup as bf16, row stride 72 shorts (144B, 16B-aligned), XOR-swizzled 16B blocks
  __shared__ __align__(16) unsigned short ts[128*72];
  // per-wave g1 bounce, bf16 [row][d], stride 72 shorts, XOR-swizzled
  __shared__ __align__(16) unsigned short gbuf[4][16*72];

  const int tid = threadIdx.x, wid = tid >> 6, lane = tid & 63;
  const int b = blockIdx.x*4 + wid;
  const int r = lane & 15, h = lane >> 4;

  // ---- stage tsup -> LDS bf16 (each thread: one half-row of 32 elems) ----
  {
    int k = tid >> 1, d0 = (tid & 1) * 32;
    const float4* src = reinterpret_cast<const float4*>(tsupg + k*64 + d0);
    unsigned int swz = (unsigned)(k & 3) << 4;
    char* rowp = (char*)&ts[k*72];
    #pragma unroll
    for (int i = 0; i < 8; ++i){
      float4 v = src[i];
      u32x2 p;
      p[0] = (unsigned)f2bf(v.x) | ((unsigned)f2bf(v.y) << 16);
      p[1] = (unsigned)f2bf(v.z) | ((unsigned)f2bf(v.w) << 16);
      *reinterpret_cast<u32x2*>(rowp + ((unsigned)((d0 + 4*i)*2) ^ swz)) = p;
    }
  }

  // ---- per-wave prologue: indices, gather-sum (s, sq, u), local branch ----
  int k0 = cat[b*128 + lane];
  int k1 = cat[b*128 + 64 + lane];

  float s = 0.f, sq = 0.f, u = 0.f;
  #pragma unroll 8
  for (int l = 0; l < 64; ++l){
    int kk = __shfl(k0, l);
    float e = emb[kk*64 + lane];
    float t = tsupg[kk*64 + lane];
    s += e; sq += e*e; u += t;
  }
  #pragma unroll 8
  for (int l = 0; l < 64; ++l){
    int kk = __shfl(k1, l);
    float e = emb[kk*64 + lane];
    float t = tsupg[kk*64 + lane];
    s += e; sq += e*e; u += t;
  }
  u += acc_b[lane];                       // u[b][lane]

  float loc0 = 0.5f*(s*s - sq);
  float a1v = 0.f;
  #pragma unroll 8
  for (int d = 0; d < 64; ++d) a1v += __shfl(loc0, d) * lwT[d*64 + lane];
  a1v = fmaxf(a1v + lb[lane], 0.f);
  float loc2 = 0.f;
  #pragma unroll 8
  for (int d = 0; d < 64; ++d) loc2 += __shfl(a1v, d) * lwT[4096 + d*64 + lane];
  loc2 += lb[64 + lane];                  // loc2[b][lane]

  // ---- redistribute u into A-fragment form: uf[kc*8+j] = u[kc*32+h*8+j] ----
  float uf[16];
  #pragma unroll
  for (int kc = 0; kc < 2; ++kc)
    #pragma unroll
    for (int j = 0; j < 8; ++j)
      uf[kc*8 + j] = __shfl(u, kc*32 + h*8 + j);

  // ---- layer-2 accumulator init: gb1[e] + loc2[e], e = mt*16 + h*4 + reg ----
  f32x4 c2i[4];
  #pragma unroll
  for (int mt = 0; mt < 4; ++mt){
    float4 gv = *reinterpret_cast<const float4*>(gbias + 64 + mt*16 + h*4);
    f32x4 t;
    t[0] = gv.x + __shfl(loc2, mt*16 + h*4 + 0);
    t[1] = gv.y + __shfl(loc2, mt*16 + h*4 + 1);
    t[2] = gv.z + __shfl(loc2, mt*16 + h*4 + 2);
    t[3] = gv.w + __shfl(loc2, mt*16 + h*4 + 3);
    c2i[mt] = t;
  }

  float gb0v[4];
  #pragma unroll
  for (int nt = 0; nt < 4; ++nt) gb0v[nt] = gbias[nt*16 + r];

  // ---- weight fragments (lane r holds row nt*16+r, elems kc*32+h*8+j) ----
  bf16x8 w0[4][2], w1[4][2];
  #pragma unroll
  for (int nt = 0; nt < 4; ++nt){
    #pragma unroll
    for (int kc = 0; kc < 2; ++kc){
      const float* p0 = gwp + (nt*16 + r)*64 + kc*32 + h*8;
      float4 a = *reinterpret_cast<const float4*>(p0);
      float4 c = *reinterpret_cast<const float4*>(p0 + 4);
      bf16x8 v;
      v[0]=(short)f2bf(a.x); v[1]=(short)f2bf(a.y); v[2]=(short)f2bf(a.z); v[3]=(short)f2bf(a.w);
      v[4]=(short)f2bf(c.x); v[5]=(short)f2bf(c.y); v[6]=(short)f2bf(c.z); v[7]=(short)f2bf(c.w);
      w0[nt][kc] = v;
      a = *reinterpret_cast<const float4*>(p0 + 4096);
      c = *reinterpret_cast<const float4*>(p0 + 4100);
      v[0]=(short)f2bf(a.x); v[1]=(short)f2bf(a.y); v[2]=(short)f2bf(a.z); v[3]=(short)f2bf(a.w);
      v[4]=(short)f2bf(c.x); v[5]=(short)f2bf(c.y); v[6]=(short)f2bf(c.z); v[7]=(short)f2bf(c.w);
      w1[nt][kc] = v;
    }
  }

  __syncthreads();   // ts staged

  char* gbase = (char*)&gbuf[wid][0];
  const char* myrow = gbase + r*144;
  const unsigned int rsw = (unsigned)(r & 3) << 4;

  for (int tl = 0; tl < 8; ++tl){
    const int rowbase = b*128 + tl*16;
    int kk = __shfl(tl < 4 ? k0 : k1, (tl & 3)*16 + r);

    // ---- A0: g0 = relu(u + t[kk])  (2 x ds_read_b128 from swizzled ts) ----
    const char* trow = (const char*)&ts[kk*72];
    const unsigned int ksw = (unsigned)(kk & 3) << 4;
    bf16x8 a0[2];
    #pragma unroll
    for (int kc = 0; kc < 2; ++kc){
      uint4 wv = *reinterpret_cast<const uint4*>(trow + ((unsigned)(kc*64 + h*16) ^ ksw));
      unsigned int ow[4];
      const unsigned int* wp = &wv.x;
      #pragma unroll
      for (int q = 0; q < 4; ++q){
        unsigned int wq = wp[q];
        float lo = __uint_as_float(wq << 16)          + uf[kc*8 + 2*q];
        float hi = __uint_as_float(wq & 0xffff0000u)  + uf[kc*8 + 2*q + 1];
        lo = fmaxf(lo, 0.f); hi = fmaxf(hi, 0.f);
        ow[q] = (unsigned)f2bf(lo) | ((unsigned)f2bf(hi) << 16);
      }
      uint4 packed; packed.x=ow[0]; packed.y=ow[1]; packed.z=ow[2]; packed.w=ow[3];
      a0[kc] = __builtin_bit_cast(bf16x8, packed);
    }

    // ---- layer 1: D[row=h*4+reg][d=nt*16+r] ----
    f32x4 acc1[4];
    #pragma unroll
    for (int nt = 0; nt < 4; ++nt){ acc1[nt][0]=gb0v[nt]; acc1[nt][1]=gb0v[nt]; acc1[nt][2]=gb0v[nt]; acc1[nt][3]=gb0v[nt]; }
    #pragma unroll
    for (int kc = 0; kc < 2; ++kc)
      #pragma unroll
      for (int nt = 0; nt < 4; ++nt)
        acc1[nt] = __builtin_amdgcn_mfma_f32_16x16x32_bf16(a0[kc], w0[nt][kc], acc1[nt], 0, 0, 0);

    // ---- relu -> bf16 -> gbuf[row][d] (swizzled scalar b16 writes) ----
    #pragma unroll
    for (int nt = 0; nt < 4; ++nt){
      #pragma unroll
      for (int reg = 0; reg < 4; ++reg){
        int row = h*4 + reg;   // row&3 == reg
        unsigned short bv = f2bf(fmaxf(acc1[nt][reg], 0.f));
        *reinterpret_cast<unsigned short*>(gbase + row*144 + ((unsigned)(nt*32 + r*2) ^ ((unsigned)reg << 4))) = bv;
      }
    }

    // ---- A1: lane needs g1[row=r][d=kc*32+h*8+j] (2 x ds_read_b128) ----
    bf16x8 a1[2];
    #pragma unroll
    for (int kc = 0; kc < 2; ++kc)
      a1[kc] = __builtin_bit_cast(bf16x8,
                 *reinterpret_cast<const uint4*>(myrow + ((unsigned)(kc*64 + h*16) ^ rsw)));

    // ---- layer 2 TRANSPOSED: acc2[mt] = W1_blk . G1^T  ->  g2[r][mt*16+h*4+reg]
    f32x4 acc2[4];
    #pragma unroll
    for (int mt = 0; mt < 4; ++mt) acc2[mt] = c2i[mt];
    #pragma unroll
    for (int kc = 0; kc < 2; ++kc)
      #pragma unroll
      for (int mt = 0; mt < 4; ++mt)
        acc2[mt] = __builtin_amdgcn_mfma_f32_16x16x32_bf16(w1[mt][kc], a1[kc], acc2[mt], 0, 0, 0);

    // ---- store: out[rowbase+r][mt*16+h*4 .. +3] = 0.5*acc2 (float4) ----
    float* orow = out + (size_t)(rowbase + r)*64 + h*4;
    #pragma unroll
    for (int mt = 0; mt < 4; ++mt){
      float4 st;
      st.x = 0.5f*acc2[mt][0]; st.y = 0.5f*acc2[mt][1];
      st.z = 0.5f*acc2[mt][2]; st.w = 0.5f*acc2[mt][3];
      *reinterpret_cast<float4*>(orow + mt*16) = st;
    }
  }
}

extern "C" void kernel_launch(void* const* d_in, const int* in_sizes, int n_in,
                              void* d_out, int out_size, void* d_ws, size_t ws_size,
                              hipStream_t stream) {
  const int*   cat   = (const int*)  d_in[0];
  const float* emb   = (const float*)d_in[1];
  const float* acc_w = (const float*)d_in[2];
  const float* acc_b = (const float*)d_in[3];
  const float* gw    = (const float*)d_in[4];
  const float* gb    = (const float*)d_in[5];
  const float* lw    = (const float*)d_in[6];
  const float* lb    = (const float*)d_in[7];
  float* out = (float*)d_out;

  const int B = in_sizes[0] / 128;       // 4096

  float* ws   = (float*)d_ws;
  float* tsup = ws;                      // 128*64
  float* lwT  = ws + 8192;               // 2*64*64

  hipLaunchKernelGGL(prep_kernel, dim3(130), dim3(64), 0, stream,
                     emb, acc_w, lw, tsup, lwT);
  hipLaunchKernelGGL(fused_kernel, dim3(B/4), dim3(256), 0, stream,
                     cat, emb, tsup, acc_b, lwT, lb, gw, gb, out);
}

// Round 3
// 53.252 us; speedup vs baseline: 1.3159x; 1.2432x over previous
//
#include <hip/hip_runtime.h>
#include <hip/hip_bf16.h>

// CatEmbedder: B=4096, L=128, D=64, PROBE=1 -> 1/129, ALPHA=0.5
//   tsup[k] = (emb_table[k] @ acc_w) / 129              (128 x 64)
//   u[b]    = sum_l tsup[idx[b,l]] + acc_b
//   g0      = relu(u[b] + tsup[idx[b,l]])
//   g2      = relu(g0 @ gw0^T + gb0) @ gw1^T + gb1
//   loc     = 0.5*(s^2 - sum e^2) -> 2-layer MLP (lwT, lb)
//   out     = 0.5*(g2_mm + gb1 + loc2)   [gb1+lb1 prefolded into loc2g]

typedef __attribute__((ext_vector_type(8))) short bf16x8;
typedef __attribute__((ext_vector_type(4))) float f32x4;
typedef __attribute__((ext_vector_type(2))) unsigned int u32x2;

#define RECIP129 (1.0f/129.0f)

static __device__ __forceinline__ unsigned short f2bf(float x){
  unsigned int u = __float_as_uint(x);
  u += 0x7fffu + ((u >> 16) & 1u);     // RNE
  return (unsigned short)(u >> 16);
}
static __device__ __forceinline__ unsigned int cvt_pk_bf16(float lo, float hi){
  unsigned int r;
  asm("v_cvt_pk_bf16_f32 %0, %1, %2" : "=v"(r) : "v"(lo), "v"(hi));
  return r;
}

// ---------------- prep: tsup (f32), lwT, MFMA weight fragments --------------
__global__ __launch_bounds__(64) void prep_kernel(const float* __restrict__ emb,
                                                  const float* __restrict__ acc_w,
                                                  const float* __restrict__ lw,
                                                  const float* __restrict__ gw,
                                                  float* __restrict__ tsup,
                                                  float* __restrict__ lwT,
                                                  uint4* __restrict__ wfrag){
  int e = threadIdx.x;
  int blk = blockIdx.x;
  if (blk < 128){
    float acc = 0.f;
    #pragma unroll
    for (int d = 0; d < 64; ++d) acc += emb[blk*64 + d] * acc_w[d*64 + e];
    tsup[blk*64 + e] = acc * RECIP129;
  } else if (blk < 130){
    int layer = blk - 128;
    const float* w = lw + layer*4096;
    float* wt = lwT + layer*4096;
    #pragma unroll
    for (int d = 0; d < 64; ++d) wt[d*64 + e] = w[e*64 + d];
  } else {
    int f = blk - 130;                  // 0..15 : layer*8 + nt*2 + kc
    int layer = f >> 3, nt = (f >> 1) & 3, kc = f & 1;
    int r = e & 15, h = e >> 4;
    const float* p0 = gw + layer*4096 + (nt*16 + r)*64 + kc*32 + h*8;
    float4 a = *reinterpret_cast<const float4*>(p0);
    float4 c = *reinterpret_cast<const float4*>(p0 + 4);
    uint4 v;
    v.x = (unsigned)f2bf(a.x) | ((unsigned)f2bf(a.y) << 16);
    v.y = (unsigned)f2bf(a.z) | ((unsigned)f2bf(a.w) << 16);
    v.z = (unsigned)f2bf(c.x) | ((unsigned)f2bf(c.y) << 16);
    v.w = (unsigned)f2bf(c.z) | ((unsigned)f2bf(c.w) << 16);
    wfrag[f*64 + e] = v;
  }
}

// ---------------- per-b (parallel): u_pg[b], loc2g[b] -----------------------
__global__ __launch_bounds__(256) void perb_kernel(const int*   __restrict__ cat,
                                                   const float* __restrict__ emb,
                                                   const float* __restrict__ tsup,
                                                   const float* __restrict__ acc_b,
                                                   const float* __restrict__ lwT,
                                                   const float* __restrict__ lb,
                                                   const float* __restrict__ gbias,
                                                   float* __restrict__ u_out,
                                                   float* __restrict__ loc2g){
  __shared__ float part[4][192];
  __shared__ float loc0s[64];
  __shared__ float a1s[64];
  const int tid = threadIdx.x, wid = tid >> 6, lane = tid & 63;
  const int b = blockIdx.x;

  int ki = (lane < 32) ? cat[b*128 + wid*32 + lane] : 0;
  float s = 0.f, sq = 0.f, tu = 0.f;
  #pragma unroll 8
  for (int i = 0; i < 32; ++i){
    int kk = __shfl(ki, i);
    float e = emb[kk*64 + lane];
    float t = tsup[kk*64 + lane];
    s += e; sq += e*e; tu += t;
  }
  part[wid][lane]       = s;
  part[wid][64 + lane]  = sq;
  part[wid][128 + lane] = tu;
  __syncthreads();

  if (tid < 64){
    float vs = part[0][tid] + part[1][tid] + part[2][tid] + part[3][tid];
    float vq = part[0][64+tid] + part[1][64+tid] + part[2][64+tid] + part[3][64+tid];
    loc0s[tid] = 0.5f*(vs*vs - vq);
  } else if (tid < 128){
    int d = tid - 64;
    float vu = part[0][128+d] + part[1][128+d] + part[2][128+d] + part[3][128+d];
    u_out[(size_t)b*64 + d] = vu + acc_b[d];
  }
  __syncthreads();

  // local layer 1 (k split across waves)
  {
    float pa = 0.f;
    #pragma unroll
    for (int i = 0; i < 16; ++i){
      int k = wid*16 + i;
      pa += loc0s[k] * lwT[k*64 + lane];
    }
    part[wid][lane] = pa;
  }
  __syncthreads();
  if (tid < 64){
    float a = part[0][tid] + part[1][tid] + part[2][tid] + part[3][tid];
    a1s[tid] = fmaxf(a + lb[tid], 0.f);
  }
  __syncthreads();

  // local layer 2
  {
    float pa = 0.f;
    #pragma unroll
    for (int i = 0; i < 16; ++i){
      int k = wid*16 + i;
      pa += a1s[k] * lwT[4096 + k*64 + lane];
    }
    part[wid][lane] = pa;
  }
  __syncthreads();
  if (tid < 64){
    float a = part[0][tid] + part[1][tid] + part[2][tid] + part[3][tid];
    loc2g[(size_t)b*64 + tid] = a + lb[64 + tid] + gbias[64 + tid];
  }
}

// ---------------- main: per-(b,l) 2-layer MLP via MFMA ----------------------
__global__ __launch_bounds__(256) void fused_kernel(
    const int*   __restrict__ cat,
    const float* __restrict__ tsupg,
    const float* __restrict__ u_pg,
    const float* __restrict__ loc2g,
    const uint4* __restrict__ wfragg,
    const float* __restrict__ gbias,
    float*       __restrict__ out)
{
  __shared__ __align__(16) unsigned short ts[128*72];      // bf16 tsup, swizzled
  __shared__ __align__(16) unsigned short gbuf[4][16*72];  // per-wave g1 bounce

  const int tid = threadIdx.x, wid = tid >> 6, lane = tid & 63;
  const int b = blockIdx.x*4 + wid;
  const int r = lane & 15, h = lane >> 4;

  // ---- stage tsup -> LDS bf16 (swizzled 16B blocks) ----
  {
    int k = tid >> 1, d0 = (tid & 1) * 32;
    const float4* src = reinterpret_cast<const float4*>(tsupg + k*64 + d0);
    unsigned int swz = (unsigned)(k & 3) << 4;
    char* rowp = (char*)&ts[k*72];
    #pragma unroll
    for (int i = 0; i < 8; ++i){
      float4 v = src[i];
      u32x2 p;
      p[0] = cvt_pk_bf16(v.x, v.y);
      p[1] = cvt_pk_bf16(v.z, v.w);
      *reinterpret_cast<u32x2*>(rowp + ((unsigned)((d0 + 4*i)*2) ^ swz)) = p;
    }
  }

  int k0 = cat[b*128 + lane];
  int k1 = cat[b*128 + 64 + lane];

  // ---- uf: u[b][kc*32+h*8+j] ----
  float uf[16];
  #pragma unroll
  for (int kc = 0; kc < 2; ++kc){
    const float* up = u_pg + (size_t)b*64 + kc*32 + h*8;
    float4 a = *reinterpret_cast<const float4*>(up);
    float4 c = *reinterpret_cast<const float4*>(up + 4);
    uf[kc*8+0]=a.x; uf[kc*8+1]=a.y; uf[kc*8+2]=a.z; uf[kc*8+3]=a.w;
    uf[kc*8+4]=c.x; uf[kc*8+5]=c.y; uf[kc*8+6]=c.z; uf[kc*8+7]=c.w;
  }

  // ---- c2i = loc2g[b][mt*16+h*4 .. +3]  (gb1+lb1 already folded) ----
  f32x4 c2i[4];
  #pragma unroll
  for (int mt = 0; mt < 4; ++mt){
    float4 lv = *reinterpret_cast<const float4*>(loc2g + (size_t)b*64 + mt*16 + h*4);
    f32x4 t; t[0]=lv.x; t[1]=lv.y; t[2]=lv.z; t[3]=lv.w;
    c2i[mt] = t;
  }

  float gb0v[4];
  #pragma unroll
  for (int nt = 0; nt < 4; ++nt) gb0v[nt] = gbias[nt*16 + r];

  // ---- weight fragments: 16 coalesced uint4 loads ----
  bf16x8 w0[4][2], w1[4][2];
  #pragma unroll
  for (int nt = 0; nt < 4; ++nt)
    #pragma unroll
    for (int kc = 0; kc < 2; ++kc){
      w0[nt][kc] = __builtin_bit_cast(bf16x8, wfragg[(nt*2 + kc)*64 + lane]);
      w1[nt][kc] = __builtin_bit_cast(bf16x8, wfragg[(8 + nt*2 + kc)*64 + lane]);
    }

  __syncthreads();   // ts staged

  char* gbase = (char*)&gbuf[wid][0];
  const char* myrow = gbase + r*144;
  const unsigned int rsw = (unsigned)(r & 3) << 4;

  for (int tl = 0; tl < 8; ++tl){
    const int rowbase = b*128 + tl*16;
    int kk = __shfl(tl < 4 ? k0 : k1, (tl & 3)*16 + r);

    // ---- A0: g0 = relu(u + t[kk]) ----
    const char* trow = (const char*)&ts[kk*72];
    const unsigned int ksw = (unsigned)(kk & 3) << 4;
    bf16x8 a0[2];
    #pragma unroll
    for (int kc = 0; kc < 2; ++kc){
      uint4 wv = *reinterpret_cast<const uint4*>(trow + ((unsigned)(kc*64 + h*16) ^ ksw));
      unsigned int ow[4];
      const unsigned int* wp = &wv.x;
      #pragma unroll
      for (int q = 0; q < 4; ++q){
        unsigned int wq = wp[q];
        float lo = fmaxf(__uint_as_float(wq << 16)         + uf[kc*8 + 2*q],     0.f);
        float hi = fmaxf(__uint_as_float(wq & 0xffff0000u) + uf[kc*8 + 2*q + 1], 0.f);
        ow[q] = cvt_pk_bf16(lo, hi);
      }
      uint4 packed; packed.x=ow[0]; packed.y=ow[1]; packed.z=ow[2]; packed.w=ow[3];
      a0[kc] = __builtin_bit_cast(bf16x8, packed);
    }

    // ---- layer 1: D[row=h*4+reg][col=nt*16+r] ----
    f32x4 acc1[4];
    #pragma unroll
    for (int nt = 0; nt < 4; ++nt){ acc1[nt][0]=gb0v[nt]; acc1[nt][1]=gb0v[nt]; acc1[nt][2]=gb0v[nt]; acc1[nt][3]=gb0v[nt]; }
    #pragma unroll
    for (int kc = 0; kc < 2; ++kc)
      #pragma unroll
      for (int nt = 0; nt < 4; ++nt)
        acc1[nt] = __builtin_amdgcn_mfma_f32_16x16x32_bf16(a0[kc], w0[nt][kc], acc1[nt], 0, 0, 0);

    // ---- relu -> bf16 -> gbuf[row][d] ----
    #pragma unroll
    for (int nt = 0; nt < 4; ++nt){
      #pragma unroll
      for (int reg = 0; reg < 4; ++reg){
        int row = h*4 + reg;
        unsigned short bv = f2bf(fmaxf(acc1[nt][reg], 0.f));
        *reinterpret_cast<unsigned short*>(gbase + row*144 + ((unsigned)(nt*32 + r*2) ^ ((unsigned)reg << 4))) = bv;
      }
    }

    // ---- A1: g1[row=r][d=kc*32+h*8+j] ----
    bf16x8 a1[2];
    #pragma unroll
    for (int kc = 0; kc < 2; ++kc)
      a1[kc] = __builtin_bit_cast(bf16x8,
                 *reinterpret_cast<const uint4*>(myrow + ((unsigned)(kc*64 + h*16) ^ rsw)));

    // ---- layer 2 transposed: g2[r][mt*16+h*4+reg] ----
    f32x4 acc2[4];
    #pragma unroll
    for (int mt = 0; mt < 4; ++mt) acc2[mt] = c2i[mt];
    #pragma unroll
    for (int kc = 0; kc < 2; ++kc)
      #pragma unroll
      for (int mt = 0; mt < 4; ++mt)
        acc2[mt] = __builtin_amdgcn_mfma_f32_16x16x32_bf16(w1[mt][kc], a1[kc], acc2[mt], 0, 0, 0);

    // ---- store ----
    float* orow = out + (size_t)(rowbase + r)*64 + h*4;
    #pragma unroll
    for (int mt = 0; mt < 4; ++mt){
      float4 st;
      st.x = 0.5f*acc2[mt][0]; st.y = 0.5f*acc2[mt][1];
      st.z = 0.5f*acc2[mt][2]; st.w = 0.5f*acc2[mt][3];
      *reinterpret_cast<float4*>(orow + mt*16) = st;
    }
  }
}

extern "C" void kernel_launch(void* const* d_in, const int* in_sizes, int n_in,
                              void* d_out, int out_size, void* d_ws, size_t ws_size,
                              hipStream_t stream) {
  const int*   cat   = (const int*)  d_in[0];
  const float* emb   = (const float*)d_in[1];
  const float* acc_w = (const float*)d_in[2];
  const float* acc_b = (const float*)d_in[3];
  const float* gw    = (const float*)d_in[4];
  const float* gb    = (const float*)d_in[5];
  const float* lw    = (const float*)d_in[6];
  const float* lb    = (const float*)d_in[7];
  float* out = (float*)d_out;

  const int B = in_sizes[0] / 128;       // 4096

  float* ws    = (float*)d_ws;
  float* tsup  = ws;                     // 8192
  float* lwT   = ws + 8192;              // 8192
  uint4* wfrag = (uint4*)(ws + 16384);   // 16*64 uint4 = 4096 floats
  float* u_pg  = ws + 20480;             // B*64
  float* loc2g = u_pg + (size_t)B*64;    // B*64

  hipLaunchKernelGGL(prep_kernel, dim3(146), dim3(64), 0, stream,
                     emb, acc_w, lw, gw, tsup, lwT, wfrag);
  hipLaunchKernelGGL(perb_kernel, dim3(B), dim3(256), 0, stream,
                     cat, emb, tsup, acc_b, lwT, lb, gb, u_pg, loc2g);
  hipLaunchKernelGGL(fused_kernel, dim3(B/4), dim3(256), 0, stream,
                     cat, tsup, u_pg, loc2g, wfrag, gb, out);
}

// Round 4
// 51.788 us; speedup vs baseline: 1.3531x; 1.0283x over previous
//
#include <hip/hip_runtime.h>
#include <hip/hip_bf16.h>

// CatEmbedder: B=4096, L=128, D=64, PROBE=1 -> 1/129, ALPHA=0.5
//   tsup[k] = (emb_table[k] @ acc_w) / 129              (128 x 64)
//   s[b]    = sum_l emb[idx], u[b] = (s @ acc_w)/129 + acc_b   (linearity)
//   g0      = relu(u[b] + tsup[idx[b,l]])
//   g2      = relu(g0 @ gw0^T + gb0) @ gw1^T + gb1
//   loc     = 0.5*(s^2 - sum e^2) -> 2-layer MLP (lwT, lb)
//   out     = (0.5*W1)·g1 + 0.5*(gb1 + loc2)    [prescaled]
// Both MFMA layers computed TRANSPOSED (weights as A-operand) so the
// inter-layer transpose is 4x ds_write_b64 + 2x ds_read_b128 per tile.

typedef __attribute__((ext_vector_type(8))) short bf16x8;
typedef __attribute__((ext_vector_type(4))) float f32x4;
typedef __attribute__((ext_vector_type(2))) unsigned int u32x2;

#define RECIP129 (1.0f/129.0f)

static __device__ __forceinline__ unsigned short f2bf(float x){
  unsigned int u = __float_as_uint(x);
  u += 0x7fffu + ((u >> 16) & 1u);     // RNE
  return (unsigned short)(u >> 16);
}
static __device__ __forceinline__ unsigned int cvt_pk_bf16(float lo, float hi){
  unsigned int r;
  asm("v_cvt_pk_bf16_f32 %0, %1, %2" : "=v"(r) : "v"(lo), "v"(hi));
  return r;
}

// ---------------- prep: tsup (f32), lwT, MFMA weight fragments --------------
__global__ __launch_bounds__(64) void prep_kernel(const float* __restrict__ emb,
                                                  const float* __restrict__ acc_w,
                                                  const float* __restrict__ lw,
                                                  const float* __restrict__ gw,
                                                  float* __restrict__ tsup,
                                                  float* __restrict__ lwT,
                                                  uint4* __restrict__ wfrag){
  int e = threadIdx.x;
  int blk = blockIdx.x;
  if (blk < 128){
    float acc = 0.f;
    #pragma unroll
    for (int d = 0; d < 64; ++d) acc += emb[blk*64 + d] * acc_w[d*64 + e];
    tsup[blk*64 + e] = acc * RECIP129;
  } else if (blk < 130){
    int layer = blk - 128;
    const float* w = lw + layer*4096;
    float* wt = lwT + layer*4096;
    #pragma unroll
    for (int d = 0; d < 64; ++d) wt[d*64 + e] = w[e*64 + d];
  } else {
    int f = blk - 130;                  // 0..15 : layer*8 + nt*2 + kc
    int layer = f >> 3, nt = (f >> 1) & 3, kc = f & 1;
    float scale = layer ? 0.5f : 1.0f;  // fold ALPHA into W1 (exact in bf16)
    int r = e & 15, h = e >> 4;
    const float* p0 = gw + layer*4096 + (nt*16 + r)*64 + kc*32 + h*8;
    float4 a = *reinterpret_cast<const float4*>(p0);
    float4 c = *reinterpret_cast<const float4*>(p0 + 4);
    uint4 v;
    v.x = (unsigned)f2bf(scale*a.x) | ((unsigned)f2bf(scale*a.y) << 16);
    v.y = (unsigned)f2bf(scale*a.z) | ((unsigned)f2bf(scale*a.w) << 16);
    v.z = (unsigned)f2bf(scale*c.x) | ((unsigned)f2bf(scale*c.y) << 16);
    v.w = (unsigned)f2bf(scale*c.z) | ((unsigned)f2bf(scale*c.w) << 16);
    wfrag[f*64 + e] = v;
  }
}

// ---------------- per-b (parallel): u_pg[b], loc2g[b] -----------------------
__global__ __launch_bounds__(256) void perb_kernel(const int*   __restrict__ cat,
                                                   const float* __restrict__ emb,
                                                   const float* __restrict__ acc_w,
                                                   const float* __restrict__ acc_b,
                                                   const float* __restrict__ lwT,
                                                   const float* __restrict__ lb,
                                                   const float* __restrict__ gbias,
                                                   float* __restrict__ u_out,
                                                   float* __restrict__ loc2g){
  __shared__ float part[4][128];
  __shared__ float s_lds[64];
  __shared__ float loc0s[64];
  __shared__ float a1s[64];
  const int tid = threadIdx.x, wid = tid >> 6, lane = tid & 63;
  const int b = blockIdx.x;

  int ki = (lane < 32) ? cat[b*128 + wid*32 + lane] : 0;
  float s = 0.f, sq = 0.f;
  #pragma unroll 8
  for (int i = 0; i < 32; ++i){
    int kk = __shfl(ki, i);
    float e = emb[kk*64 + lane];
    s += e; sq += e*e;
  }
  part[wid][lane]      = s;
  part[wid][64 + lane] = sq;
  __syncthreads();

  if (tid < 64){
    float vs = part[0][tid] + part[1][tid] + part[2][tid] + part[3][tid];
    float vq = part[0][64+tid] + part[1][64+tid] + part[2][64+tid] + part[3][64+tid];
    s_lds[tid] = vs;
    loc0s[tid] = 0.5f*(vs*vs - vq);
  }
  __syncthreads();

  // u matvec + local layer 1 (k split across waves)
  {
    float pu = 0.f, pa = 0.f;
    #pragma unroll
    for (int i = 0; i < 16; ++i){
      int k = wid*16 + i;
      pu += s_lds[k] * acc_w[k*64 + lane];
      pa += loc0s[k] * lwT[k*64 + lane];
    }
    part[wid][lane]      = pu;
    part[wid][64 + lane] = pa;
  }
  __syncthreads();
  if (tid < 64){
    float vu = part[0][tid] + part[1][tid] + part[2][tid] + part[3][tid];
    u_out[(size_t)b*64 + tid] = vu * RECIP129 + acc_b[tid];
  } else if (tid < 128){
    int d = tid - 64;
    float a = part[0][64+d] + part[1][64+d] + part[2][64+d] + part[3][64+d];
    a1s[d] = fmaxf(a + lb[d], 0.f);
  }
  __syncthreads();

  // local layer 2
  {
    float pa = 0.f;
    #pragma unroll
    for (int i = 0; i < 16; ++i){
      int k = wid*16 + i;
      pa += a1s[k] * lwT[4096 + k*64 + lane];
    }
    part[wid][lane] = pa;
  }
  __syncthreads();
  if (tid < 64){
    float a = part[0][tid] + part[1][tid] + part[2][tid] + part[3][tid];
    loc2g[(size_t)b*64 + tid] = 0.5f*(a + lb[64 + tid] + gbias[64 + tid]);
  }
}

// ---------------- main: per-(b,l) 2-layer MLP via MFMA (both transposed) ----
__global__ __launch_bounds__(256) void fused_kernel(
    const int*   __restrict__ cat,
    const float* __restrict__ tsupg,
    const float* __restrict__ u_pg,
    const float* __restrict__ loc2g,
    const uint4* __restrict__ wfragg,
    const float* __restrict__ gbias,
    float*       __restrict__ out)
{
  __shared__ __align__(16) unsigned short ts[128*72];      // bf16 tsup, swizzled
  __shared__ __align__(16) unsigned short gbuf[4][16*64];  // g1 rows, 128B, swizzled

  const int tid = threadIdx.x, wid = tid >> 6, lane = tid & 63;
  const int b = blockIdx.x*4 + wid;
  const int r = lane & 15, h = lane >> 4;

  // ---- stage tsup -> LDS bf16 (swizzled 16B blocks) ----
  {
    int k = tid >> 1, d0 = (tid & 1) * 32;
    const float4* src = reinterpret_cast<const float4*>(tsupg + k*64 + d0);
    unsigned int swz = (unsigned)(k & 3) << 4;
    char* rowp = (char*)&ts[k*72];
    #pragma unroll
    for (int i = 0; i < 8; ++i){
      float4 v = src[i];
      u32x2 p;
      p[0] = cvt_pk_bf16(v.x, v.y);
      p[1] = cvt_pk_bf16(v.z, v.w);
      *reinterpret_cast<u32x2*>(rowp + ((unsigned)((d0 + 4*i)*2) ^ swz)) = p;
    }
  }

  int k0 = cat[b*128 + lane];
  int k1 = cat[b*128 + 64 + lane];

  // ---- uf: u[b][kc*32+h*8+j] (A0 build) ----
  float uf[16];
  #pragma unroll
  for (int kc = 0; kc < 2; ++kc){
    const float* up = u_pg + (size_t)b*64 + kc*32 + h*8;
    float4 a = *reinterpret_cast<const float4*>(up);
    float4 c = *reinterpret_cast<const float4*>(up + 4);
    uf[kc*8+0]=a.x; uf[kc*8+1]=a.y; uf[kc*8+2]=a.z; uf[kc*8+3]=a.w;
    uf[kc*8+4]=c.x; uf[kc*8+5]=c.y; uf[kc*8+6]=c.z; uf[kc*8+7]=c.w;
  }

  // ---- layer-1 bias (transposed D: lane holds dims nt*16+h*4+reg) ----
  f32x4 gb0f[4];
  #pragma unroll
  for (int nt = 0; nt < 4; ++nt){
    float4 gv = *reinterpret_cast<const float4*>(gbias + nt*16 + h*4);
    f32x4 t; t[0]=gv.x; t[1]=gv.y; t[2]=gv.z; t[3]=gv.w;
    gb0f[nt] = t;
  }

  // ---- layer-2 accumulator init: 0.5*(gb1+loc2) prefolded in loc2g ----
  f32x4 c2i[4];
  #pragma unroll
  for (int mt = 0; mt < 4; ++mt){
    float4 lv = *reinterpret_cast<const float4*>(loc2g + (size_t)b*64 + mt*16 + h*4);
    f32x4 t; t[0]=lv.x; t[1]=lv.y; t[2]=lv.z; t[3]=lv.w;
    c2i[mt] = t;
  }

  // ---- weight fragments: 16 coalesced uint4 loads (w1 prescaled by 0.5) ----
  bf16x8 w0[4][2], w1[4][2];
  #pragma unroll
  for (int nt = 0; nt < 4; ++nt)
    #pragma unroll
    for (int kc = 0; kc < 2; ++kc){
      w0[nt][kc] = __builtin_bit_cast(bf16x8, wfragg[(nt*2 + kc)*64 + lane]);
      w1[nt][kc] = __builtin_bit_cast(bf16x8, wfragg[(8 + nt*2 + kc)*64 + lane]);
    }

  __syncthreads();   // ts staged

  char* myrowW = (char*)&gbuf[wid][0] + r*128;
  const unsigned int rsw8 = (unsigned)(r & 7) << 4;

  for (int tl = 0; tl < 8; ++tl){
    const int rowbase = b*128 + tl*16;
    int kk = __shfl(tl < 4 ? k0 : k1, (tl & 3)*16 + r);

    // ---- A0 (as B-operand): g0[row r][d=kc*32+h*8+j] = relu(u + t[kk]) ----
    const char* trow = (const char*)&ts[kk*72];
    const unsigned int ksw = (unsigned)(kk & 3) << 4;
    bf16x8 a0[2];
    #pragma unroll
    for (int kc = 0; kc < 2; ++kc){
      uint4 wv = *reinterpret_cast<const uint4*>(trow + ((unsigned)(kc*64 + h*16) ^ ksw));
      unsigned int ow[4];
      const unsigned int* wp = &wv.x;
      #pragma unroll
      for (int q = 0; q < 4; ++q){
        unsigned int wq = wp[q];
        float lo = fmaxf(__uint_as_float(wq << 16)         + uf[kc*8 + 2*q],     0.f);
        float hi = fmaxf(__uint_as_float(wq & 0xffff0000u) + uf[kc*8 + 2*q + 1], 0.f);
        ow[q] = cvt_pk_bf16(lo, hi);
      }
      uint4 packed; packed.x=ow[0]; packed.y=ow[1]; packed.z=ow[2]; packed.w=ow[3];
      a0[kc] = __builtin_bit_cast(bf16x8, packed);
    }

    // ---- layer 1 TRANSPOSED: D = W0 . G0^T -> lane: g1[r][nt*16+h*4+reg] ----
    f32x4 acc1[4];
    #pragma unroll
    for (int nt = 0; nt < 4; ++nt) acc1[nt] = gb0f[nt];
    #pragma unroll
    for (int kc = 0; kc < 2; ++kc)
      #pragma unroll
      for (int nt = 0; nt < 4; ++nt)
        acc1[nt] = __builtin_amdgcn_mfma_f32_16x16x32_bf16(w0[nt][kc], a0[kc], acc1[nt], 0, 0, 0);

    // ---- relu+pack -> row-major g1 (4x ds_write_b64, swizzled) ----
    #pragma unroll
    for (int nt = 0; nt < 4; ++nt){
      u32x2 p;
      p[0] = cvt_pk_bf16(fmaxf(acc1[nt][0], 0.f), fmaxf(acc1[nt][1], 0.f));
      p[1] = cvt_pk_bf16(fmaxf(acc1[nt][2], 0.f), fmaxf(acc1[nt][3], 0.f));
      *reinterpret_cast<u32x2*>(myrowW + ((unsigned)(nt*32 + h*8) ^ rsw8)) = p;
    }

    // ---- A1 (as B-operand): g1[row r][d=kc*32+h*8+j] (2x ds_read_b128) ----
    bf16x8 a1[2];
    #pragma unroll
    for (int kc = 0; kc < 2; ++kc)
      a1[kc] = __builtin_bit_cast(bf16x8,
                 *reinterpret_cast<const uint4*>(myrowW + ((unsigned)(kc*64 + h*16) ^ rsw8)));

    // ---- layer 2 transposed: g2[r][mt*16+h*4+reg], W1 pre-halved ----
    f32x4 acc2[4];
    #pragma unroll
    for (int mt = 0; mt < 4; ++mt) acc2[mt] = c2i[mt];
    #pragma unroll
    for (int kc = 0; kc < 2; ++kc)
      #pragma unroll
      for (int mt = 0; mt < 4; ++mt)
        acc2[mt] = __builtin_amdgcn_mfma_f32_16x16x32_bf16(w1[mt][kc], a1[kc], acc2[mt], 0, 0, 0);

    // ---- store: out[rowbase+r][mt*16+h*4 .. +3] (float4, no scale) ----
    float* orow = out + (size_t)(rowbase + r)*64 + h*4;
    #pragma unroll
    for (int mt = 0; mt < 4; ++mt){
      float4 st;
      st.x = acc2[mt][0]; st.y = acc2[mt][1];
      st.z = acc2[mt][2]; st.w = acc2[mt][3];
      *reinterpret_cast<float4*>(orow + mt*16) = st;
    }
  }
}

extern "C" void kernel_launch(void* const* d_in, const int* in_sizes, int n_in,
                              void* d_out, int out_size, void* d_ws, size_t ws_size,
                              hipStream_t stream) {
  const int*   cat   = (const int*)  d_in[0];
  const float* emb   = (const float*)d_in[1];
  const float* acc_w = (const float*)d_in[2];
  const float* acc_b = (const float*)d_in[3];
  const float* gw    = (const float*)d_in[4];
  const float* gb    = (const float*)d_in[5];
  const float* lw    = (const float*)d_in[6];
  const float* lb    = (const float*)d_in[7];
  float* out = (float*)d_out;

  const int B = in_sizes[0] / 128;       // 4096

  float* ws    = (float*)d_ws;
  float* tsup  = ws;                     // 8192
  float* lwT   = ws + 8192;              // 8192
  uint4* wfrag = (uint4*)(ws + 16384);   // 16*64 uint4 = 4096 floats
  float* u_pg  = ws + 20480;             // B*64
  float* loc2g = u_pg + (size_t)B*64;    // B*64

  hipLaunchKernelGGL(prep_kernel, dim3(146), dim3(64), 0, stream,
                     emb, acc_w, lw, gw, tsup, lwT, wfrag);
  hipLaunchKernelGGL(perb_kernel, dim3(B), dim3(256), 0, stream,
                     cat, emb, acc_w, acc_b, lwT, lb, gb, u_pg, loc2g);
  hipLaunchKernelGGL(fused_kernel, dim3(B/4), dim3(256), 0, stream,
                     cat, tsup, u_pg, loc2g, wfrag, gb, out);
}